// Round 4
// baseline (762.351 us; speedup 1.0000x reference)
//
#include <hip/hip_runtime.h>
#include <hip/hip_bf16.h>
#include <math.h>

#define B_ 128
#define T_ 512
#define H_ 1024
#define L_ 23
#define EMS 24      // padded emission row stride (floats)
#define NINF (-1.0f/0.0f)

__device__ __forceinline__ float rdl(float v, int l) {
  return __int_as_float(__builtin_amdgcn_readlane(__float_as_int(v), l));
}
__device__ __forceinline__ float rdfl(float v) {
  return __int_as_float(__builtin_amdgcn_readfirstlane(__float_as_int(v)));
}

// ---------------- Kernel 1: emissions = hs @ W + b ----------------
// 1024 blocks x 256 thr. Block = 64 rows x 4 k-quarters (quarter == wave,
// so W addresses are wave-uniform -> s_load; hidden via direct global
// float4, 8 consecutive per group = one full 128B line per lane per group,
// explicitly double-buffered). No LDS in the main loop -> no lgkm mixing.
__global__ __launch_bounds__(256) void emis_kernel(
    const float* __restrict__ hs, const float* __restrict__ W,
    const float* __restrict__ bias, float* __restrict__ em) {
  __shared__ float comb[3 * 64 * L_];
  const int tid = threadIdx.x;
  const int r = tid & 63;
  const int q = tid >> 6;          // k-quarter == wave id
  const int row = blockIdx.x * 64 + r;
  // quarter base: 256 floats = 64 float4
  const float4* x4 = (const float4*)(hs + (size_t)row * H_) + q * 64;
  const float* Wq = W + (size_t)__builtin_amdgcn_readfirstlane(q * 256) * L_;

  float acc[L_];
#pragma unroll
  for (int l = 0; l < L_; ++l) acc[l] = 0.f;

#define FMA4(vv, wb)                                                     \
  { const float* wp = (wb);                                              \
    _Pragma("unroll") for (int l = 0; l < L_; ++l)                       \
      acc[l] = fmaf((vv).x, wp[l], acc[l]);                              \
    _Pragma("unroll") for (int l = 0; l < L_; ++l)                       \
      acc[l] = fmaf((vv).y, wp[L_ + l], acc[l]);                         \
    _Pragma("unroll") for (int l = 0; l < L_; ++l)                       \
      acc[l] = fmaf((vv).z, wp[2 * L_ + l], acc[l]);                     \
    _Pragma("unroll") for (int l = 0; l < L_; ++l)                       \
      acc[l] = fmaf((vv).w, wp[3 * L_ + l], acc[l]); }

  float4 va[8], vb[8];
#pragma unroll
  for (int u = 0; u < 8; ++u) va[u] = x4[u];

  for (int gp = 0; gp < 4; ++gp) {   // rolled: body ~1.5K insts, fits I$
    {
      const int g = 2 * gp;
      if (g < 7) {
#pragma unroll
        for (int u = 0; u < 8; ++u) vb[u] = x4[(g + 1) * 8 + u];
      }
      const float* wg = Wq + (size_t)(g * 32) * L_;
#pragma unroll
      for (int u = 0; u < 8; ++u) FMA4(va[u], wg + (size_t)(u * 4) * L_);
    }
    {
      const int g = 2 * gp + 1;
      if (g < 7) {
#pragma unroll
        for (int u = 0; u < 8; ++u) va[u] = x4[(g + 1) * 8 + u];
      }
      const float* wg = Wq + (size_t)(g * 32) * L_;
#pragma unroll
      for (int u = 0; u < 8; ++u) FMA4(vb[u], wg + (size_t)(u * 4) * L_);
    }
  }

  // 4-way combine via LDS (same summation order as before: q0+q1+q2+q3+bias)
  if (q > 0) {
    float* p = comb + ((q - 1) * 64 + r) * L_;
#pragma unroll
    for (int l = 0; l < L_; ++l) p[l] = acc[l];
  }
  __syncthreads();
  if (q == 0) {
#pragma unroll
    for (int l = 0; l < L_; ++l)
      acc[l] = acc[l] + comb[(0 * 64 + r) * L_ + l] + comb[(1 * 64 + r) * L_ + l]
             + comb[(2 * 64 + r) * L_ + l] + bias[l];
    float4* op = (float4*)(em + (size_t)row * EMS);
    op[0] = make_float4(acc[0], acc[1], acc[2], acc[3]);
    op[1] = make_float4(acc[4], acc[5], acc[6], acc[7]);
    op[2] = make_float4(acc[8], acc[9], acc[10], acc[11]);
    op[3] = make_float4(acc[12], acc[13], acc[14], acc[15]);
    op[4] = make_float4(acc[16], acc[17], acc[18], acc[19]);
    op[5] = make_float4(acc[20], acc[21], acc[22], 0.0f);
  }
}

// ---------------- Kernel 2: CRF fwd/logZ (role 0) + Viterbi (role 1) -------
// Grid 256: block = (batch, role). 2 waves: wave0 compute, wave1 stage
// emissions (64-row chunks, double-buffered) + gold score (role 0).
__global__ __launch_bounds__(128) void crf_kernel(
    const float* __restrict__ em, const int* __restrict__ am,
    const int* __restrict__ labels, const float* __restrict__ startT,
    const float* __restrict__ endT, const float* __restrict__ trans,
    float* __restrict__ llh, float* __restrict__ out) {
  __shared__ float emb_lds[2][64 * EMS];
  __shared__ int bp_lds[(T_ - 1) * L_];
  __shared__ int tags_sh[T_];
  __shared__ float score_sh;

  const int role = blockIdx.x & 1;
  const int b = blockIdx.x >> 1;
  const int wid = threadIdx.x >> 6;
  const int lane = threadIdx.x & 63;
  const int eml = (lane < L_) ? lane : 0;
  const float* emb = em + (size_t)b * T_ * EMS;
  const int* amb = am + b * T_;
  const int* lab = labels + b * T_;

  // per-lane persistent state (wave0)
  float state = NINF;            // alpha (role0) / viterbi score (role1)
  float colT[L_];                // exp(T[i][lane]) or T[i][lane]
  float st_r = 0.f, end_r = 0.f;
  if (wid == 0) {
    st_r = startT[eml];
    end_r = endT[eml];
#pragma unroll
    for (int i = 0; i < L_; ++i) {
      float tv = trans[i * L_ + eml];
      colT[i] = (role == 0) ? __expf(tv) : tv;
    }
  }

  int av = amb[lane];            // mask values for chunk 0 (all lanes)

  for (int c = 0; c < 8; ++c) {
    if (wid == 1) {
      const float* src = emb + c * (64 * EMS);
      float4 v[6];
#pragma unroll
      for (int i = 0; i < 6; ++i)
        v[i] = *(const float4*)(src + i * 256 + lane * 4);
#pragma unroll
      for (int i = 0; i < 6; ++i)
        *(float4*)&emb_lds[c & 1][i * 256 + lane * 4] = v[i];
    }
    __syncthreads();
    if (wid == 0) {
      int av_nxt = (c < 7) ? amb[(c + 1) * 64 + lane] : 0;
      unsigned long long mkb = __ballot(av == 1);
      const float* eb = &emb_lds[c & 1][0];
      int s0 = 0;
      if (c == 0) {
        state = (lane < L_) ? st_r + eb[lane] : NINF;
        s0 = 1;
      }
      if (role == 0) {
        // ---- forward (logsumexp) ----
#pragma unroll 4
        for (int s = s0; s < 64; ++s) {
          float ee = eb[s * EMS + eml];
          bool mk = (mkb >> s) & 1ull;
          float m0 = rdfl(state);
          float ex = __expf(state - m0);   // lanes >= L: exp(-inf)=0
          float p0 = 0.f, p1 = 0.f, p2 = 0.f, p3 = 0.f;
#pragma unroll
          for (int i = 0; i < 20; i += 4) {
            p0 = fmaf(rdl(ex, i + 0), colT[i + 0], p0);
            p1 = fmaf(rdl(ex, i + 1), colT[i + 1], p1);
            p2 = fmaf(rdl(ex, i + 2), colT[i + 2], p2);
            p3 = fmaf(rdl(ex, i + 3), colT[i + 3], p3);
          }
          p0 = fmaf(rdl(ex, 20), colT[20], p0);
          p1 = fmaf(rdl(ex, 21), colT[21], p1);
          p2 = fmaf(rdl(ex, 22), colT[22], p2);
          float sum = (p0 + p1) + (p2 + p3);
          float nxt = m0 + __logf(sum) + ee;
          state = (mk && lane < L_) ? nxt : state;
        }
      } else {
        // ---- viterbi forward ----
#pragma unroll 2
        for (int s = s0; s < 64; ++s) {
          int t = c * 64 + s;
          float ee = eb[s * EMS + eml];
          bool mk = (mkb >> s) & 1ull;
          float ci[L_];
#pragma unroll
          for (int i = 0; i < L_; ++i) ci[i] = rdl(state, i) + colT[i];
          // pairwise max tree
          float m1[12];
#pragma unroll
          for (int i = 0; i < 11; ++i) m1[i] = fmaxf(ci[2 * i], ci[2 * i + 1]);
          m1[11] = ci[22];
          float m2[6];
#pragma unroll
          for (int i = 0; i < 6; ++i) m2[i] = fmaxf(m1[2 * i], m1[2 * i + 1]);
          float m3a = fmaxf(m2[0], m2[1]), m3b = fmaxf(m2[2], m2[3]),
                m3c = fmaxf(m2[4], m2[5]);
          float best = fmaxf(fmaxf(m3a, m3b), m3c);
          int bi = 22;
#pragma unroll
          for (int i = 21; i >= 0; --i) bi = (ci[i] == best) ? i : bi;
          float snew = best + ee;
          int bpv = mk ? bi : lane;
          state = (mk && lane < L_) ? snew : state;
          if (lane < L_) bp_lds[(t - 1) * L_ + lane] = bpv;
        }
      }
      av = av_nxt;
    }
  }

  // gold score on wave1 (role 0) — overlaps wave0's last chunk
  if (wid == 1 && role == 0) {
    float sc = 0.f;
    int cnt = 0;
#pragma unroll
    for (int it = 0; it < 8; ++it) {
      int t = it * 64 + lane;
      int mk = (amb[t] == 1);
      cnt += mk;
      int lt = lab[t];
      float emt = emb[t * EMS + lt];
      if (t == 0) sc += startT[lt] + emt;
      else if (mk) sc += trans[lab[t - 1] * L_ + lt] + emt;
    }
#pragma unroll
    for (int off = 32; off >= 1; off >>= 1) {
      sc += __shfl_xor(sc, off);
      cnt += __shfl_xor(cnt, off);
    }
    sc += endT[lab[cnt - 1]];
    if (lane == 0) score_sh = sc;
  }
  __syncthreads();

  if (wid == 0) {
    if (role == 0) {
      // logZ (true max for final reduce)
      float v = (lane < L_) ? state + end_r : NINF;
      float mx = v;
#pragma unroll
      for (int off = 32; off >= 1; off >>= 1) mx = fmaxf(mx, __shfl_xor(mx, off));
      float e2 = __expf(v - mx);
#pragma unroll
      for (int off = 32; off >= 1; off >>= 1) e2 += __shfl_xor(e2, off);
      if (lane == 0) llh[b] = score_sh - (mx + __logf(e2));
    } else {
      // final argmax (first-index)
      float v = (lane < L_) ? state + end_r : NINF;
      float mx = v;
#pragma unroll
      for (int off = 32; off >= 1; off >>= 1) mx = fmaxf(mx, __shfl_xor(mx, off));
      int cand = (v == mx && lane < L_) ? lane : 64;
#pragma unroll
      for (int off = 32; off >= 1; off >>= 1) cand = min(cand, __shfl_xor(cand, off));
      int cur = __builtin_amdgcn_readfirstlane(cand);
      if (lane == 0) tags_sh[T_ - 1] = cur;
      // backtrack: all 23 lanes load the bp row, scalar readlane chain
#pragma unroll 8
      for (int t = T_ - 2; t >= 0; --t) {
        int row = bp_lds[t * L_ + eml];
        cur = __builtin_amdgcn_readlane(row, cur);
        if (lane == 0) tags_sh[t] = cur;
      }
      // coalesced prediction stores
      for (int t = lane; t < T_; t += 64) {
        float o = (amb[t] == 1) ? (float)tags_sh[t] : 0.0f;
        out[1 + b * T_ + t] = o;
      }
    }
  }
}

// ---------------- Kernel 3: loss = -mean(llh) ----------------
__global__ void finalize_kernel(const float* __restrict__ llh,
                                float* __restrict__ out) {
  int lane = threadIdx.x;
  float v = llh[lane] + llh[lane + 64];
#pragma unroll
  for (int off = 32; off >= 1; off >>= 1) v += __shfl_xor(v, off);
  if (lane == 0) out[0] = -v * (1.0f / (float)B_);
}

extern "C" void kernel_launch(void* const* d_in, const int* in_sizes, int n_in,
                              void* d_out, int out_size, void* d_ws, size_t ws_size,
                              hipStream_t stream) {
  const float* hs     = (const float*)d_in[0];
  const int*   am     = (const int*)d_in[1];
  const int*   labels = (const int*)d_in[2];
  const float* W      = (const float*)d_in[3];
  const float* bias   = (const float*)d_in[4];
  const float* startT = (const float*)d_in[5];
  const float* endT   = (const float*)d_in[6];
  const float* trans  = (const float*)d_in[7];
  float* out = (float*)d_out;

  float* em  = (float*)d_ws;                      // 65536 * 24 floats = 6.29 MB
  float* llh = em + (size_t)B_ * T_ * EMS;        // 128 floats

  emis_kernel<<<B_ * T_ / 64, 256, 0, stream>>>(hs, W, bias, em);
  crf_kernel<<<2 * B_, 128, 0, stream>>>(em, am, labels, startT, endT, trans, llh, out);
  finalize_kernel<<<1, 64, 0, stream>>>(llh, out);
}

// Round 5
// 672.324 us; speedup vs baseline: 1.1339x; 1.1339x over previous
//
#include <hip/hip_runtime.h>
#include <hip/hip_bf16.h>
#include <math.h>

#define B_ 128
#define T_ 512
#define H_ 1024
#define L_ 23
#define EMS 24      // padded emission row stride (floats)
#define NINF (-1.0f/0.0f)
#define TS 68       // emis LDS tile row stride (floats): 272B, 16B-aligned, 2-way max

__device__ __forceinline__ float rdl(float v, int l) {
  return __int_as_float(__builtin_amdgcn_readlane(__float_as_int(v), l));
}
__device__ __forceinline__ float rdfl(float v) {
  return __int_as_float(__builtin_amdgcn_readfirstlane(__float_as_int(v)));
}

// ---------------- Kernel 1: emissions = hs @ W + b ----------------
// 1024 blocks x 256 thr. Block = 64 rows; K in 16 chunks of 64.
// Stage: thread (sr=tid>>4, sk=tid&15) loads rows {sr,sr+16,sr+32,sr+48},
// float4 at k-slot sk -> coalesced 256B segments; ds_write to padded tile.
// Compute: thread (r=tid&63, q=tid>>6) owns row r, k-span [c*64+q*16,+16):
// 4x ds_read_b128 -> sched_barrier -> 368 FMAs with W via wave-uniform s_load.
// Only one lgkm drain per chunk; no ds/SMEM interleave inside FMA stream.
__global__ __launch_bounds__(256) void emis_kernel(
    const float* __restrict__ hs, const float* __restrict__ W,
    const float* __restrict__ bias, float* __restrict__ em) {
  __shared__ float tile[2][64 * TS];
  const int tid = threadIdx.x;
  const int r = tid & 63;
  const int q = tid >> 6;
  const int qk = __builtin_amdgcn_readfirstlane(q * 16);  // wave-uniform
  const int sr = tid >> 4;
  const int sk = tid & 15;
  const float* gsrc = hs + (size_t)(blockIdx.x * 64 + sr) * H_ + sk * 4;

  float acc[L_];
#pragma unroll
  for (int l = 0; l < L_; ++l) acc[l] = 0.f;

  float4 g[4];
  // stage chunk 0
#pragma unroll
  for (int m = 0; m < 4; ++m)
    g[m] = *(const float4*)(gsrc + (size_t)(16 * m) * H_);
#pragma unroll
  for (int m = 0; m < 4; ++m)
    *(float4*)&tile[0][(sr + 16 * m) * TS + sk * 4] = g[m];
  __syncthreads();

  for (int c = 0; c < 16; ++c) {
    const int buf = c & 1;
    // prefetch chunk c+1 to regs (global, vmcnt stream)
    if (c < 15) {
#pragma unroll
      for (int m = 0; m < 4; ++m)
        g[m] = *(const float4*)(gsrc + (size_t)(16 * m) * H_ + (c + 1) * 64);
    }
    // LDS -> regs: this wave's 16 k-values for row r
    float hv[16];
    const float* tp = &tile[buf][r * TS + qk];
#pragma unroll
    for (int p = 0; p < 4; ++p)
      *(float4*)&hv[p * 4] = *(const float4*)(tp + p * 4);
    __builtin_amdgcn_sched_barrier(0);   // keep ds_reads out of FMA stream
    // pure FMA + s_load(W) stream
    const float* wk = W + (size_t)(c * 64 + qk) * L_;
#pragma unroll
    for (int kk = 0; kk < 16; ++kk) {
      const float x = hv[kk];
      const float* wr = wk + kk * L_;    // uniform -> s_load
#pragma unroll
      for (int l = 0; l < L_; ++l) acc[l] = fmaf(x, wr[l], acc[l]);
    }
    // publish staged chunk c+1
    if (c < 15) {
#pragma unroll
      for (int m = 0; m < 4; ++m)
        *(float4*)&tile[buf ^ 1][(sr + 16 * m) * TS + sk * 4] = g[m];
      __syncthreads();
    }
  }

  // 4-way combine (overlay comb on tile; all tile reads are done)
  __syncthreads();
  float* comb = (float*)tile;
  if (q > 0) {
    float* p = comb + ((q - 1) * 64 + r) * L_;
#pragma unroll
    for (int l = 0; l < L_; ++l) p[l] = acc[l];
  }
  __syncthreads();
  if (q == 0) {
#pragma unroll
    for (int l = 0; l < L_; ++l)
      acc[l] = acc[l] + comb[(0 * 64 + r) * L_ + l] + comb[(1 * 64 + r) * L_ + l]
             + comb[(2 * 64 + r) * L_ + l] + bias[l];
    const int row = blockIdx.x * 64 + r;
    float4* op = (float4*)(em + (size_t)row * EMS);
    op[0] = make_float4(acc[0], acc[1], acc[2], acc[3]);
    op[1] = make_float4(acc[4], acc[5], acc[6], acc[7]);
    op[2] = make_float4(acc[8], acc[9], acc[10], acc[11]);
    op[3] = make_float4(acc[12], acc[13], acc[14], acc[15]);
    op[4] = make_float4(acc[16], acc[17], acc[18], acc[19]);
    op[5] = make_float4(acc[20], acc[21], acc[22], 0.0f);
  }
}

// ---------------- Kernel 2: CRF fwd/logZ (role 0) + Viterbi (role 1) -------
// Grid 256: block = (batch, role). 2 waves: wave0 compute, wave1 stage
// emissions (64-row chunks, double-buffered) + gold score (role 0).
// bp_lds slot t (t>=1) = backpointer for step t; slot 0 unused (c0 mask trick).
__global__ __launch_bounds__(128) void crf_kernel(
    const float* __restrict__ em, const int* __restrict__ am,
    const int* __restrict__ labels, const float* __restrict__ startT,
    const float* __restrict__ endT, const float* __restrict__ trans,
    float* __restrict__ llh, float* __restrict__ out) {
  __shared__ float emb_lds[2][64 * EMS];
  __shared__ int bp_lds[T_ * L_];
  __shared__ int tags_sh[T_];
  __shared__ float score_sh;

  const int role = blockIdx.x & 1;
  const int b = blockIdx.x >> 1;
  const int wid = threadIdx.x >> 6;
  const int lane = threadIdx.x & 63;
  const int eml = (lane < L_) ? lane : 0;
  const float* emb = em + (size_t)b * T_ * EMS;
  const int* amb = am + b * T_;
  const int* lab = labels + b * T_;

  float state = NINF;            // alpha (role0) / viterbi score (role1)
  float colT[L_];                // exp(T[i][lane]) or T[i][lane]
  float st_r = 0.f, end_r = 0.f;
  if (wid == 0) {
    st_r = startT[eml];
    end_r = endT[eml];
#pragma unroll
    for (int i = 0; i < L_; ++i) {
      float tv = trans[i * L_ + eml];
      colT[i] = (role == 0) ? __expf(tv) : tv;
    }
  }

  int av = amb[lane];            // mask values for chunk 0 (all lanes)

  for (int c = 0; c < 8; ++c) {
    if (wid == 1) {
      const float* src = emb + c * (64 * EMS);
      float4 v[6];
#pragma unroll
      for (int i = 0; i < 6; ++i)
        v[i] = *(const float4*)(src + i * 256 + lane * 4);
#pragma unroll
      for (int i = 0; i < 6; ++i)
        *(float4*)&emb_lds[c & 1][i * 256 + lane * 4] = v[i];
    }
    __syncthreads();
    if (wid == 0) {
      int av_nxt = (c < 7) ? amb[(c + 1) * 64 + lane] : 0;
      unsigned long long mkb = __ballot(av == 1);
      const float* eb = &emb_lds[c & 1][0];
      if (c == 0) {
        state = (lane < L_) ? st_r + eb[lane] : NINF;
        mkb &= ~1ull;            // step 0 is a no-op (state already init'd)
      }
      if (role == 0) {
        // ---- forward (logsumexp) ----
#pragma unroll 4
        for (int s = 0; s < 64; ++s) {
          float ee = eb[s * EMS + eml];
          bool mk = (mkb >> s) & 1ull;
          float m0 = rdfl(state);
          float ex = __expf(state - m0);   // lanes >= L: exp(-inf)=0
          float p0 = 0.f, p1 = 0.f, p2 = 0.f, p3 = 0.f;
#pragma unroll
          for (int i = 0; i < 20; i += 4) {
            p0 = fmaf(rdl(ex, i + 0), colT[i + 0], p0);
            p1 = fmaf(rdl(ex, i + 1), colT[i + 1], p1);
            p2 = fmaf(rdl(ex, i + 2), colT[i + 2], p2);
            p3 = fmaf(rdl(ex, i + 3), colT[i + 3], p3);
          }
          p0 = fmaf(rdl(ex, 20), colT[20], p0);
          p1 = fmaf(rdl(ex, 21), colT[21], p1);
          p2 = fmaf(rdl(ex, 22), colT[22], p2);
          float sum = (p0 + p1) + (p2 + p3);
          float nxt = m0 + __logf(sum) + ee;
          state = (mk && lane < L_) ? nxt : state;
        }
      } else {
        // ---- viterbi forward ----
#pragma unroll 2
        for (int s = 0; s < 64; ++s) {
          int t = c * 64 + s;
          float ee = eb[s * EMS + eml];
          bool mk = (mkb >> s) & 1ull;
          float ci[L_];
#pragma unroll
          for (int i = 0; i < L_; ++i) ci[i] = rdl(state, i) + colT[i];
          // pairwise max tree
          float m1[12];
#pragma unroll
          for (int i = 0; i < 11; ++i) m1[i] = fmaxf(ci[2 * i], ci[2 * i + 1]);
          m1[11] = ci[22];
          float m2[6];
#pragma unroll
          for (int i = 0; i < 6; ++i) m2[i] = fmaxf(m1[2 * i], m1[2 * i + 1]);
          float m3a = fmaxf(m2[0], m2[1]), m3b = fmaxf(m2[2], m2[3]),
                m3c = fmaxf(m2[4], m2[5]);
          float best = fmaxf(fmaxf(m3a, m3b), m3c);
          int bi = 22;
#pragma unroll
          for (int i = 21; i >= 0; --i) bi = (ci[i] == best) ? i : bi;
          float snew = best + ee;
          int bpv = mk ? bi : lane;
          state = (mk && lane < L_) ? snew : state;
          if (lane < L_) bp_lds[t * L_ + lane] = bpv;   // t=0 slot unused
        }
      }
      av = av_nxt;
    }
  }

  // gold score on wave1 (role 0) — overlaps wave0's last chunk
  if (wid == 1 && role == 0) {
    float sc = 0.f;
    int cnt = 0;
#pragma unroll
    for (int it = 0; it < 8; ++it) {
      int t = it * 64 + lane;
      int mk = (amb[t] == 1);
      cnt += mk;
      int lt = lab[t];
      float emt = emb[t * EMS + lt];
      if (t == 0) sc += startT[lt] + emt;
      else if (mk) sc += trans[lab[t - 1] * L_ + lt] + emt;
    }
#pragma unroll
    for (int off = 32; off >= 1; off >>= 1) {
      sc += __shfl_xor(sc, off);
      cnt += __shfl_xor(cnt, off);
    }
    sc += endT[lab[cnt - 1]];
    if (lane == 0) score_sh = sc;
  }
  __syncthreads();

  if (wid == 0) {
    if (role == 0) {
      float v = (lane < L_) ? state + end_r : NINF;
      float mx = v;
#pragma unroll
      for (int off = 32; off >= 1; off >>= 1) mx = fmaxf(mx, __shfl_xor(mx, off));
      float e2 = __expf(v - mx);
#pragma unroll
      for (int off = 32; off >= 1; off >>= 1) e2 += __shfl_xor(e2, off);
      if (lane == 0) llh[b] = score_sh - (mx + __logf(e2));
    } else {
      float v = (lane < L_) ? state + end_r : NINF;
      float mx = v;
#pragma unroll
      for (int off = 32; off >= 1; off >>= 1) mx = fmaxf(mx, __shfl_xor(mx, off));
      int cand = (v == mx && lane < L_) ? lane : 64;
#pragma unroll
      for (int off = 32; off >= 1; off >>= 1) cand = min(cand, __shfl_xor(cand, off));
      int cur = __builtin_amdgcn_readfirstlane(cand);
      if (lane == 0) tags_sh[T_ - 1] = cur;
      // backtrack: lanes hold bp row, scalar readlane chain (step t+1 at slot t+1)
#pragma unroll 8
      for (int t = T_ - 2; t >= 0; --t) {
        int row = bp_lds[(t + 1) * L_ + eml];
        cur = __builtin_amdgcn_readlane(row, cur);
        if (lane == 0) tags_sh[t] = cur;
      }
      for (int t = lane; t < T_; t += 64) {
        float o = (amb[t] == 1) ? (float)tags_sh[t] : 0.0f;
        out[1 + b * T_ + t] = o;
      }
    }
  }
}

// ---------------- Kernel 3: loss = -mean(llh) ----------------
__global__ void finalize_kernel(const float* __restrict__ llh,
                                float* __restrict__ out) {
  int lane = threadIdx.x;
  float v = llh[lane] + llh[lane + 64];
#pragma unroll
  for (int off = 32; off >= 1; off >>= 1) v += __shfl_xor(v, off);
  if (lane == 0) out[0] = -v * (1.0f / (float)B_);
}

extern "C" void kernel_launch(void* const* d_in, const int* in_sizes, int n_in,
                              void* d_out, int out_size, void* d_ws, size_t ws_size,
                              hipStream_t stream) {
  const float* hs     = (const float*)d_in[0];
  const int*   am     = (const int*)d_in[1];
  const int*   labels = (const int*)d_in[2];
  const float* W      = (const float*)d_in[3];
  const float* bias   = (const float*)d_in[4];
  const float* startT = (const float*)d_in[5];
  const float* endT   = (const float*)d_in[6];
  const float* trans  = (const float*)d_in[7];
  float* out = (float*)d_out;

  float* em  = (float*)d_ws;                      // 65536 * 24 floats = 6.29 MB
  float* llh = em + (size_t)B_ * T_ * EMS;        // 128 floats

  emis_kernel<<<B_ * T_ / 64, 256, 0, stream>>>(hs, W, bias, em);
  crf_kernel<<<2 * B_, 128, 0, stream>>>(em, am, labels, startT, endT, trans, llh, out);
  finalize_kernel<<<1, 64, 0, stream>>>(llh, out);
}